// Round 2
// baseline (293.420 us; speedup 1.0000x reference)
//
#include <hip/hip_runtime.h>

#define D     2048
#define NEXP  4
#define BLK   256
#define NWAVE 4
#define EPSV  1e-5f

__device__ __forceinline__ void dot24(float hbv, int d,
    const float4* __restrict__ Wb4, const float4* __restrict__ Wm4,
    const float4* __restrict__ Wr4, float acc[24])
{
    float4 wb = Wb4[d];
    acc[0] += hbv * wb.x; acc[1] += hbv * wb.y; acc[2] += hbv * wb.z; acc[3] += hbv * wb.w;
    float4 wm = Wm4[d];
    acc[4] += hbv * wm.x; acc[5] += hbv * wm.y; acc[6] += hbv * wm.z; acc[7] += hbv * wm.w;
    #pragma unroll
    for (int i = 0; i < 4; ++i) {
        float4 wr = Wr4[d * 4 + i];
        acc[8 + i * 4 + 0] += hbv * wr.x;
        acc[8 + i * 4 + 1] += hbv * wr.y;
        acc[8 + i * 4 + 2] += hbv * wr.z;
        acc[8 + i * 4 + 3] += hbv * wr.w;
    }
}

__global__ __launch_bounds__(BLK) void hc_kernel(
    const float* __restrict__ lo,      // [tok, D]
    const float* __restrict__ hs,      // [tok, NEXP, D]
    const float* __restrict__ Bm,      // [1, NEXP]
    const float* __restrict__ Am,      // [NEXP, 1]
    const float* __restrict__ Ar,      // [NEXP, NEXP]
    const float* __restrict__ s_alpha, // [NEXP, NEXP]
    const float* __restrict__ s_beta,  // [1, NEXP]
    const float* __restrict__ Wb,      // [D, NEXP]
    const float* __restrict__ Wm,      // [D, NEXP]
    const float* __restrict__ Wr,      // [D, NEXP, NEXP]
    float* __restrict__ out)           // [tok, NEXP, D]
{
    __shared__ float red[NWAVE][24];
    __shared__ float stats[2][NEXP];
    __shared__ float coef[24];

    const int tid  = threadIdx.x;
    const int wave = tid >> 6;
    const int lane = tid & 63;
    const long tok = blockIdx.x;

    const float4* hs4  = (const float4*)(hs + tok * (long)(NEXP * D));
    const float4* lo4  = (const float4*)(lo + tok * (long)D);
    float4*       out4 = (float4*)(out + tok * (long)(NEXP * D));

    // ---- Phase 1: load hidden rows into REGISTERS, accumulate sum / sumsq ----
    float4 h[NEXP][2];
    float sum[NEXP], sq[NEXP];
    #pragma unroll
    for (int n = 0; n < NEXP; ++n) { sum[n] = 0.f; sq[n] = 0.f; }

    #pragma unroll
    for (int n = 0; n < NEXP; ++n) {
        #pragma unroll
        for (int k = 0; k < 2; ++k) {
            float4 v = hs4[n * (D / 4) + tid + BLK * k];
            h[n][k] = v;
            sum[n] += v.x + v.y + v.z + v.w;
            sq[n]  += v.x * v.x + v.y * v.y + v.z * v.z + v.w * v.w;
        }
    }
    #pragma unroll
    for (int n = 0; n < NEXP; ++n) {
        #pragma unroll
        for (int off = 32; off > 0; off >>= 1) {
            sum[n] += __shfl_down(sum[n], off, 64);
            sq[n]  += __shfl_down(sq[n],  off, 64);
        }
    }
    if (lane == 0) {
        #pragma unroll
        for (int n = 0; n < NEXP; ++n) {
            red[wave][n]        = sum[n];
            red[wave][NEXP + n] = sq[n];
        }
    }
    __syncthreads();
    if (tid < NEXP) {
        float s = 0.f, s2 = 0.f;
        for (int w = 0; w < NWAVE; ++w) { s += red[w][tid]; s2 += red[w][NEXP + tid]; }
        float m  = s * (1.f / D);
        float var = s2 * (1.f / D) - m * m;
        stats[0][tid] = m;
        stats[1][tid] = rsqrtf(var + EPSV);
    }
    __syncthreads();
    float mu[NEXP], rs[NEXP];
    #pragma unroll
    for (int n = 0; n < NEXP; ++n) { mu[n] = stats[0][n]; rs[n] = stats[1][n]; }

    // ---- Phase 2: H_bar dot-products against the 24 weight columns ----
    float acc[24];
    #pragma unroll
    for (int v = 0; v < 24; ++v) acc[v] = 0.f;

    const float4* Wb4 = (const float4*)Wb;
    const float4* Wm4 = (const float4*)Wm;
    const float4* Wr4 = (const float4*)Wr;

    #pragma unroll
    for (int k = 0; k < 2; ++k) {
        int d0 = 4 * (tid + BLK * k);
        float hb0 = 0.25f * ((h[0][k].x - mu[0]) * rs[0] + (h[1][k].x - mu[1]) * rs[1] +
                             (h[2][k].x - mu[2]) * rs[2] + (h[3][k].x - mu[3]) * rs[3]);
        float hb1 = 0.25f * ((h[0][k].y - mu[0]) * rs[0] + (h[1][k].y - mu[1]) * rs[1] +
                             (h[2][k].y - mu[2]) * rs[2] + (h[3][k].y - mu[3]) * rs[3]);
        float hb2 = 0.25f * ((h[0][k].z - mu[0]) * rs[0] + (h[1][k].z - mu[1]) * rs[1] +
                             (h[2][k].z - mu[2]) * rs[2] + (h[3][k].z - mu[3]) * rs[3]);
        float hb3 = 0.25f * ((h[0][k].w - mu[0]) * rs[0] + (h[1][k].w - mu[1]) * rs[1] +
                             (h[2][k].w - mu[2]) * rs[2] + (h[3][k].w - mu[3]) * rs[3]);
        dot24(hb0, d0 + 0, Wb4, Wm4, Wr4, acc);
        dot24(hb1, d0 + 1, Wb4, Wm4, Wr4, acc);
        dot24(hb2, d0 + 2, Wb4, Wm4, Wr4, acc);
        dot24(hb3, d0 + 3, Wb4, Wm4, Wr4, acc);
    }
    #pragma unroll
    for (int v = 0; v < 24; ++v) {
        #pragma unroll
        for (int off = 32; off > 0; off >>= 1)
            acc[v] += __shfl_down(acc[v], off, 64);
    }
    if (lane == 0) {
        #pragma unroll
        for (int v = 0; v < 24; ++v) red[wave][v] = acc[v];
    }
    __syncthreads();
    if (tid < 24) {
        float s = 0.f;
        for (int w = 0; w < NWAVE; ++w) s += red[w][tid];
        float t = tanhf(s);
        float c;
        if (tid < 4) {
            c = s_beta[tid] * t + Bm[tid];
        } else if (tid < 8) {
            int n = tid - 4;
            c = s_alpha[n * 4] * t + Am[n];
        } else {
            int ij = tid - 8;
            c = s_alpha[ij] * t + Ar[ij];
        }
        coef[tid] = c;
    }
    __syncthreads();

    float Bd[NEXP], Amd[NEXP], Ard[NEXP][NEXP];
    #pragma unroll
    for (int n = 0; n < NEXP; ++n) { Bd[n] = coef[n]; Amd[n] = coef[4 + n]; }
    #pragma unroll
    for (int i = 0; i < NEXP; ++i)
        #pragma unroll
        for (int j = 0; j < NEXP; ++j) Ard[i][j] = coef[8 + i * 4 + j];

    // ---- Phase 3: outputs from registers ----
    #pragma unroll
    for (int k = 0; k < 2; ++k) {
        int d4 = tid + BLK * k;
        float4 l = lo4[d4];

        float4 mx = {0.f, 0.f, 0.f, 0.f};
        #pragma unroll
        for (int n = 0; n < NEXP; ++n) {
            mx.x += Amd[n] * h[n][k].x; mx.y += Amd[n] * h[n][k].y;
            mx.z += Amd[n] * h[n][k].z; mx.w += Amd[n] * h[n][k].w;
        }
        #pragma unroll
        for (int i = 0; i < NEXP; ++i) {
            float4 o;
            o.x = Bd[i] * l.x + mx.x;
            o.y = Bd[i] * l.y + mx.y;
            o.z = Bd[i] * l.z + mx.z;
            o.w = Bd[i] * l.w + mx.w;
            #pragma unroll
            for (int j = 0; j < NEXP; ++j) {
                o.x += Ard[i][j] * h[j][k].x;
                o.y += Ard[i][j] * h[j][k].y;
                o.z += Ard[i][j] * h[j][k].z;
                o.w += Ard[i][j] * h[j][k].w;
            }
            out4[i * (D / 4) + d4] = o;
        }
    }
}

extern "C" void kernel_launch(void* const* d_in, const int* in_sizes, int n_in,
                              void* d_out, int out_size, void* d_ws, size_t ws_size,
                              hipStream_t stream) {
    const float* lo      = (const float*)d_in[0];
    const float* hs      = (const float*)d_in[1];
    const float* Bm      = (const float*)d_in[2];
    const float* Am      = (const float*)d_in[3];
    const float* Ar      = (const float*)d_in[4];
    const float* s_alpha = (const float*)d_in[5];
    const float* s_beta  = (const float*)d_in[6];
    const float* Wb      = (const float*)d_in[7];
    const float* Wm      = (const float*)d_in[8];
    const float* Wr      = (const float*)d_in[9];
    float* out = (float*)d_out;

    const int tokens = in_sizes[0] / D;   // 8192
    hc_kernel<<<tokens, BLK, 0, stream>>>(lo, hs, Bm, Am, Ar, s_alpha, s_beta,
                                          Wb, Wm, Wr, out);
}

// Round 3
// 227.539 us; speedup vs baseline: 1.2895x; 1.2895x over previous
//
#include <hip/hip_runtime.h>

#define D     2048
#define NEXP  4
#define BLK   256
#define NWAVE 4
#define EPSV  1e-5f

__device__ __forceinline__ void dot24(float hbv, int d,
    const float4* __restrict__ Wb4, const float4* __restrict__ Wm4,
    const float4* __restrict__ Wr4, float acc[24])
{
    float4 wb = Wb4[d];
    acc[0] += hbv * wb.x; acc[1] += hbv * wb.y; acc[2] += hbv * wb.z; acc[3] += hbv * wb.w;
    float4 wm = Wm4[d];
    acc[4] += hbv * wm.x; acc[5] += hbv * wm.y; acc[6] += hbv * wm.z; acc[7] += hbv * wm.w;
    #pragma unroll
    for (int i = 0; i < 4; ++i) {
        float4 wr = Wr4[d * 4 + i];
        acc[8 + i * 4 + 0] += hbv * wr.x;
        acc[8 + i * 4 + 1] += hbv * wr.y;
        acc[8 + i * 4 + 2] += hbv * wr.z;
        acc[8 + i * 4 + 3] += hbv * wr.w;
    }
}

__global__ __launch_bounds__(BLK) void hc_kernel(
    const float* __restrict__ lo,      // [tok, D]
    const float* __restrict__ hs,      // [tok, NEXP, D]
    const float* __restrict__ Bm,      // [1, NEXP]
    const float* __restrict__ Am,      // [NEXP, 1]
    const float* __restrict__ Ar,      // [NEXP, NEXP]
    const float* __restrict__ s_alpha, // [NEXP, NEXP]
    const float* __restrict__ s_beta,  // [1, NEXP]
    const float* __restrict__ Wb,      // [D, NEXP]
    const float* __restrict__ Wm,      // [D, NEXP]
    const float* __restrict__ Wr,      // [D, NEXP, NEXP]
    float* __restrict__ out)           // [tok, NEXP, D]
{
    __shared__ float h_lds[NEXP][D];   // 32 KB
    __shared__ float scr[64][25];      // 6.4 KB transpose-reduce scratch (25: bank-conflict-free)
    __shared__ float stats[2][NEXP];
    __shared__ float coef[24];

    const int tid  = threadIdx.x;
    const int wave = tid >> 6;
    const int lane = tid & 63;
    const long tok = blockIdx.x;

    const float4* hs4  = (const float4*)(hs + tok * (long)(NEXP * D));
    const float4* lo4  = (const float4*)(lo + tok * (long)D);
    float4*       out4 = (float4*)(out + tok * (long)(NEXP * D));

    // ---- Phase 1: stage hidden rows in LDS, accumulate sum / sumsq ----
    float sum[NEXP], sq[NEXP];
    #pragma unroll
    for (int n = 0; n < NEXP; ++n) { sum[n] = 0.f; sq[n] = 0.f; }

    #pragma unroll
    for (int n = 0; n < NEXP; ++n) {
        #pragma unroll
        for (int k = 0; k < 2; ++k) {
            int d4 = tid + BLK * k;                 // lane-contiguous float4
            float4 v = hs4[n * (D / 4) + d4];
            sum[n] += v.x + v.y + v.z + v.w;
            sq[n]  += v.x * v.x + v.y * v.y + v.z * v.z + v.w * v.w;
            ((float4*)h_lds[n])[d4] = v;
        }
    }
    // 2-step shfl: lane l<16 holds sum of lanes {l, l+16, l+32, l+48}
    #pragma unroll
    for (int n = 0; n < NEXP; ++n) {
        sum[n] += __shfl_down(sum[n], 32, 64);
        sum[n] += __shfl_down(sum[n], 16, 64);
        sq[n]  += __shfl_down(sq[n],  32, 64);
        sq[n]  += __shfl_down(sq[n],  16, 64);
    }
    if (lane < 16) {
        int r = wave * 16 + lane;
        #pragma unroll
        for (int n = 0; n < NEXP; ++n) {
            scr[r][n]        = sum[n];
            scr[r][NEXP + n] = sq[n];
        }
    }
    __syncthreads();
    if (tid < NEXP) {
        float s = 0.f, s2 = 0.f;
        #pragma unroll
        for (int j = 0; j < 64; ++j) { s += scr[j][tid]; s2 += scr[j][NEXP + tid]; }
        float m   = s * (1.f / D);
        float var = s2 * (1.f / D) - m * m;
        stats[0][tid] = m;
        stats[1][tid] = rsqrtf(var + EPSV);
    }
    __syncthreads();
    float mu[NEXP], rs[NEXP];
    #pragma unroll
    for (int n = 0; n < NEXP; ++n) { mu[n] = stats[0][n]; rs[n] = stats[1][n]; }

    // prefetch layer_output (needed only in phase 3) so its HBM latency hides under phase 2
    float4 lpre0 = lo4[tid];
    float4 lpre1 = lo4[tid + BLK];

    // ---- Phase 2: H_bar dot-products against the 24 weight columns ----
    float acc[24];
    #pragma unroll
    for (int v = 0; v < 24; ++v) acc[v] = 0.f;

    const float4* Wb4 = (const float4*)Wb;
    const float4* Wm4 = (const float4*)Wm;
    const float4* Wr4 = (const float4*)Wr;

    #pragma unroll
    for (int k = 0; k < 8; ++k) {                   // lane-contiguous scalar d
        int d = tid + BLK * k;
        float hb = 0.f;
        #pragma unroll
        for (int n = 0; n < NEXP; ++n) hb += (h_lds[n][d] - mu[n]) * rs[n];
        hb *= 0.25f;
        dot24(hb, d, Wb4, Wm4, Wr4, acc);
    }
    // 2-step shfl then LDS transpose-reduce
    #pragma unroll
    for (int v = 0; v < 24; ++v) {
        acc[v] += __shfl_down(acc[v], 32, 64);
        acc[v] += __shfl_down(acc[v], 16, 64);
    }
    if (lane < 16) {
        int r = wave * 16 + lane;
        #pragma unroll
        for (int v = 0; v < 24; ++v) scr[r][v] = acc[v];
    }
    __syncthreads();
    if (tid < 24) {
        float s = 0.f;
        #pragma unroll
        for (int j = 0; j < 64; ++j) s += scr[j][tid];
        float t = tanhf(s);
        float c;
        if (tid < 4) {
            c = s_beta[tid] * t + Bm[tid];
        } else if (tid < 8) {
            int n = tid - 4;
            c = s_alpha[n * 4] * t + Am[n];
        } else {
            int ij = tid - 8;
            c = s_alpha[ij] * t + Ar[ij];
        }
        coef[tid] = c;
    }
    __syncthreads();

    float Bd[NEXP], Amd[NEXP], Ard[NEXP][NEXP];
    #pragma unroll
    for (int n = 0; n < NEXP; ++n) { Bd[n] = coef[n]; Amd[n] = coef[4 + n]; }
    #pragma unroll
    for (int i = 0; i < NEXP; ++i)
        #pragma unroll
        for (int j = 0; j < NEXP; ++j) Ard[i][j] = coef[8 + i * 4 + j];

    // ---- Phase 3: outputs ----
    #pragma unroll
    for (int k = 0; k < 2; ++k) {
        int d4 = tid + BLK * k;
        float4 h[NEXP];
        #pragma unroll
        for (int n = 0; n < NEXP; ++n) h[n] = ((const float4*)h_lds[n])[d4];
        float4 l = (k == 0) ? lpre0 : lpre1;

        float4 mx = {0.f, 0.f, 0.f, 0.f};
        #pragma unroll
        for (int n = 0; n < NEXP; ++n) {
            mx.x += Amd[n] * h[n].x; mx.y += Amd[n] * h[n].y;
            mx.z += Amd[n] * h[n].z; mx.w += Amd[n] * h[n].w;
        }
        #pragma unroll
        for (int i = 0; i < NEXP; ++i) {
            float4 o;
            o.x = Bd[i] * l.x + mx.x;
            o.y = Bd[i] * l.y + mx.y;
            o.z = Bd[i] * l.z + mx.z;
            o.w = Bd[i] * l.w + mx.w;
            #pragma unroll
            for (int j = 0; j < NEXP; ++j) {
                o.x += Ard[i][j] * h[j].x;
                o.y += Ard[i][j] * h[j].y;
                o.z += Ard[i][j] * h[j].z;
                o.w += Ard[i][j] * h[j].w;
            }
            out4[i * (D / 4) + d4] = o;
        }
    }
}

extern "C" void kernel_launch(void* const* d_in, const int* in_sizes, int n_in,
                              void* d_out, int out_size, void* d_ws, size_t ws_size,
                              hipStream_t stream) {
    const float* lo      = (const float*)d_in[0];
    const float* hs      = (const float*)d_in[1];
    const float* Bm      = (const float*)d_in[2];
    const float* Am      = (const float*)d_in[3];
    const float* Ar      = (const float*)d_in[4];
    const float* s_alpha = (const float*)d_in[5];
    const float* s_beta  = (const float*)d_in[6];
    const float* Wb      = (const float*)d_in[7];
    const float* Wm      = (const float*)d_in[8];
    const float* Wr      = (const float*)d_in[9];
    float* out = (float*)d_out;

    const int tokens = in_sizes[0] / D;   // 8192
    hc_kernel<<<tokens, BLK, 0, stream>>>(lo, hs, Bm, Am, Ar, s_alpha, s_beta,
                                          Wb, Wm, Wr, out);
}

// Round 4
// 155.171 us; speedup vs baseline: 1.8909x; 1.4664x over previous
//
#include <hip/hip_runtime.h>

#define D     2048
#define NEXP  4
#define BLK   256
#define NWAVE 4
#define EPSV  1e-5f

// ---- bf16 helpers (manual, cheap) ----
__device__ __forceinline__ unsigned short f2b(float f) {
    union { float f; unsigned int u; } v; v.f = f;
    unsigned int r = (v.u + 0x7fffu + ((v.u >> 16) & 1u)) >> 16;   // RNE
    return (unsigned short)r;
}
__device__ __forceinline__ float b2f(unsigned short b) {
    union { unsigned int u; float f; } v; v.u = ((unsigned int)b) << 16;
    return v.f;
}

// ---- weight transpose: Wt[c][d], c: 0-3 Wb, 4-7 Wm, 8-23 Wr(i*4+j) ----
__global__ __launch_bounds__(256) void wt_kernel(
    const float* __restrict__ Wb, const float* __restrict__ Wm,
    const float* __restrict__ Wr, float* __restrict__ Wt)
{
    int idx = blockIdx.x * 256 + threadIdx.x;      // 24*2048 = 49152 = 192*256
    int c = idx / D;
    int d = idx % D;
    float v;
    if (c < 4)       v = Wb[d * 4 + c];
    else if (c < 8)  v = Wm[d * 4 + (c - 4)];
    else             v = Wr[d * 16 + (c - 8)];
    Wt[c * D + d] = v;
}

__global__ __launch_bounds__(BLK) void hc_kernel(
    const float* __restrict__ lo,      // [tok, D]
    const float* __restrict__ hs,      // [tok, NEXP, D]
    const float* __restrict__ Bm,      // [1, NEXP]
    const float* __restrict__ Am,      // [NEXP, 1]
    const float* __restrict__ Ar,      // [NEXP, NEXP]
    const float* __restrict__ s_alpha, // [NEXP, NEXP]
    const float* __restrict__ s_beta,  // [1, NEXP]
    const float* __restrict__ Wt,      // [24, D] transposed weights
    float* __restrict__ out)           // [tok, NEXP, D]
{
    __shared__ unsigned short h16[NEXP][D];   // 16 KB bf16 copy of hidden rows
    __shared__ float red[NWAVE][24];
    __shared__ float stats[2][NEXP];
    __shared__ float coef[24];

    const int tid  = threadIdx.x;
    const int wave = tid >> 6;
    const int lane = tid & 63;
    const long tok = blockIdx.x;

    const float4* hs4  = (const float4*)(hs + tok * (long)(NEXP * D));
    const float4* lo4  = (const float4*)(lo + tok * (long)D);
    float4*       out4 = (float4*)(out + tok * (long)(NEXP * D));

    // ---- Phase 1: load hidden rows (lane-contiguous f32x4), stats + bf16 LDS stage ----
    float sum[NEXP], sq[NEXP];
    #pragma unroll
    for (int n = 0; n < NEXP; ++n) { sum[n] = 0.f; sq[n] = 0.f; }

    #pragma unroll
    for (int n = 0; n < NEXP; ++n) {
        #pragma unroll
        for (int k = 0; k < 2; ++k) {
            int d4 = tid + BLK * k;
            float4 v = hs4[n * (D / 4) + d4];
            sum[n] += v.x + v.y + v.z + v.w;
            sq[n]  += v.x * v.x + v.y * v.y + v.z * v.z + v.w * v.w;
            ushort4 p;
            p.x = f2b(v.x); p.y = f2b(v.y); p.z = f2b(v.z); p.w = f2b(v.w);
            ((ushort4*)h16[n])[d4] = p;
        }
    }
    // prefetch layer_output (used only in phase 3)
    float4 lpre0 = lo4[tid];
    float4 lpre1 = lo4[tid + BLK];

    // full shfl tree (R1-proven)
    #pragma unroll
    for (int n = 0; n < NEXP; ++n) {
        #pragma unroll
        for (int off = 32; off > 0; off >>= 1) {
            sum[n] += __shfl_down(sum[n], off, 64);
            sq[n]  += __shfl_down(sq[n],  off, 64);
        }
    }
    if (lane == 0) {
        #pragma unroll
        for (int n = 0; n < NEXP; ++n) {
            red[wave][n]        = sum[n];
            red[wave][NEXP + n] = sq[n];
        }
    }
    __syncthreads();
    if (tid < NEXP) {
        float s = 0.f, s2 = 0.f;
        for (int w = 0; w < NWAVE; ++w) { s += red[w][tid]; s2 += red[w][NEXP + tid]; }
        float m   = s * (1.f / D);
        float var = s2 * (1.f / D) - m * m;
        stats[0][tid] = m;
        stats[1][tid] = rsqrtf(var + EPSV);
    }
    __syncthreads();
    float mu[NEXP], rs[NEXP];
    #pragma unroll
    for (int n = 0; n < NEXP; ++n) { mu[n] = stats[0][n]; rs[n] = stats[1][n]; }

    // ---- Phase 2: H_bar dots, ALL loads lane-contiguous via transposed weights ----
    float acc[24];
    #pragma unroll
    for (int v = 0; v < 24; ++v) acc[v] = 0.f;

    const float4* Wt4 = (const float4*)Wt;      // [24][512] float4

    #pragma unroll
    for (int k = 0; k < 2; ++k) {
        int d4 = tid + BLK * k;
        ushort4 a[NEXP];
        #pragma unroll
        for (int n = 0; n < NEXP; ++n) a[n] = ((const ushort4*)h16[n])[d4];
        float4 hb;
        hb.x = 0.25f * ((b2f(a[0].x) - mu[0]) * rs[0] + (b2f(a[1].x) - mu[1]) * rs[1] +
                        (b2f(a[2].x) - mu[2]) * rs[2] + (b2f(a[3].x) - mu[3]) * rs[3]);
        hb.y = 0.25f * ((b2f(a[0].y) - mu[0]) * rs[0] + (b2f(a[1].y) - mu[1]) * rs[1] +
                        (b2f(a[2].y) - mu[2]) * rs[2] + (b2f(a[3].y) - mu[3]) * rs[3]);
        hb.z = 0.25f * ((b2f(a[0].z) - mu[0]) * rs[0] + (b2f(a[1].z) - mu[1]) * rs[1] +
                        (b2f(a[2].z) - mu[2]) * rs[2] + (b2f(a[3].z) - mu[3]) * rs[3]);
        hb.w = 0.25f * ((b2f(a[0].w) - mu[0]) * rs[0] + (b2f(a[1].w) - mu[1]) * rs[1] +
                        (b2f(a[2].w) - mu[2]) * rs[2] + (b2f(a[3].w) - mu[3]) * rs[3]);
        #pragma unroll
        for (int c = 0; c < 24; ++c) {
            float4 w = Wt4[c * (D / 4) + d4];
            acc[c] += hb.x * w.x + hb.y * w.y + hb.z * w.z + hb.w * w.w;
        }
    }
    #pragma unroll
    for (int v = 0; v < 24; ++v) {
        #pragma unroll
        for (int off = 32; off > 0; off >>= 1)
            acc[v] += __shfl_down(acc[v], off, 64);
    }
    if (lane == 0) {
        #pragma unroll
        for (int v = 0; v < 24; ++v) red[wave][v] = acc[v];
    }
    __syncthreads();
    if (tid < 24) {
        float s = 0.f;
        for (int w = 0; w < NWAVE; ++w) s += red[w][tid];
        float t = tanhf(s);
        float c;
        if (tid < 4) {
            c = s_beta[tid] * t + Bm[tid];
        } else if (tid < 8) {
            int n = tid - 4;
            c = s_alpha[n * 4] * t + Am[n];
        } else {
            int ij = tid - 8;
            c = s_alpha[ij] * t + Ar[ij];
        }
        coef[tid] = c;
    }
    __syncthreads();

    float Bd[NEXP], Amd[NEXP], Ard[NEXP][NEXP];
    #pragma unroll
    for (int n = 0; n < NEXP; ++n) { Bd[n] = coef[n]; Amd[n] = coef[4 + n]; }
    #pragma unroll
    for (int i = 0; i < NEXP; ++i)
        #pragma unroll
        for (int j = 0; j < NEXP; ++j) Ard[i][j] = coef[8 + i * 4 + j];

    // ---- Phase 3: outputs from bf16 LDS + prefetched lo ----
    #pragma unroll
    for (int k = 0; k < 2; ++k) {
        int d4 = tid + BLK * k;
        float4 h[NEXP];
        #pragma unroll
        for (int n = 0; n < NEXP; ++n) {
            ushort4 a = ((const ushort4*)h16[n])[d4];
            h[n].x = b2f(a.x); h[n].y = b2f(a.y); h[n].z = b2f(a.z); h[n].w = b2f(a.w);
        }
        float4 l = (k == 0) ? lpre0 : lpre1;

        float4 mx = {0.f, 0.f, 0.f, 0.f};
        #pragma unroll
        for (int n = 0; n < NEXP; ++n) {
            mx.x += Amd[n] * h[n].x; mx.y += Amd[n] * h[n].y;
            mx.z += Amd[n] * h[n].z; mx.w += Amd[n] * h[n].w;
        }
        #pragma unroll
        for (int i = 0; i < NEXP; ++i) {
            float4 o;
            o.x = Bd[i] * l.x + mx.x;
            o.y = Bd[i] * l.y + mx.y;
            o.z = Bd[i] * l.z + mx.z;
            o.w = Bd[i] * l.w + mx.w;
            #pragma unroll
            for (int j = 0; j < NEXP; ++j) {
                o.x += Ard[i][j] * h[j].x;
                o.y += Ard[i][j] * h[j].y;
                o.z += Ard[i][j] * h[j].z;
                o.w += Ard[i][j] * h[j].w;
            }
            out4[i * (D / 4) + d4] = o;
        }
    }
}

extern "C" void kernel_launch(void* const* d_in, const int* in_sizes, int n_in,
                              void* d_out, int out_size, void* d_ws, size_t ws_size,
                              hipStream_t stream) {
    const float* lo      = (const float*)d_in[0];
    const float* hs      = (const float*)d_in[1];
    const float* Bm      = (const float*)d_in[2];
    const float* Am      = (const float*)d_in[3];
    const float* Ar      = (const float*)d_in[4];
    const float* s_alpha = (const float*)d_in[5];
    const float* s_beta  = (const float*)d_in[6];
    const float* Wb      = (const float*)d_in[7];
    const float* Wm      = (const float*)d_in[8];
    const float* Wr      = (const float*)d_in[9];
    float* out = (float*)d_out;
    float* Wt  = (float*)d_ws;                     // 24*2048*4 = 196 608 B

    wt_kernel<<<192, 256, 0, stream>>>(Wb, Wm, Wr, Wt);

    const int tokens = in_sizes[0] / D;            // 8192
    hc_kernel<<<tokens, BLK, 0, stream>>>(lo, hs, Bm, Am, Ar, s_alpha, s_beta,
                                          Wt, out);
}